// Round 3
// baseline (453.089 us; speedup 1.0000x reference)
//
#include <hip/hip_runtime.h>

typedef unsigned short u16;
typedef __bf16 bf16x8 __attribute__((ext_vector_type(8)));
typedef float floatx4 __attribute__((ext_vector_type(4)));

#define B_ 2
#define S_ 2048
#define H_ 2048
#define NH_ 16
#define BS_ 4096   // B_*S_
#define QKSTR 4096 // row stride of fused QK buffer
#define PSTR 72    // P LDS row stride (elements)

// softmax scale folded into Q at GEMM epilogue: hd^-0.5 * log2(e)
#define SCL_Q (0.08838834764831843f * 1.4426950408889634f)

// partial buffers (fixed-max softmax => partials are additive)
#define PART_CH 4194304   // floats per chunk: 8 qt * 32 bh * 128 q * 128 hd
#define LP_CH 32768       // floats per chunk: 8 * 32 * 128

__device__ __forceinline__ u16 f2bf(float f) {
  unsigned u = __float_as_uint(f);
  u += 0x7fffu + ((u >> 16) & 1u);  // RNE
  return (u16)(u >> 16);
}

__device__ __forceinline__ void gl_lds16(const void* g, void* l) {
  __builtin_amdgcn_global_load_lds((__attribute__((address_space(1))) void*)g,
                                   (__attribute__((address_space(3))) void*)l,
                                   16, 0, 0);
}

__device__ __forceinline__ floatx4 mfma16(bf16x8 a, bf16x8 b, floatx4 c) {
  return __builtin_amdgcn_mfma_f32_16x16x32_bf16(a, b, c, 0, 0, 0);
}

// ---- fused fp32->bf16 cast: X (BS*H) then Wq,Wk,Wv,Wo (H*H each)
__global__ void cast_all(const float* __restrict__ X, const float* __restrict__ Wq,
                         const float* __restrict__ Wk, const float* __restrict__ Wv,
                         const float* __restrict__ Wo, u16* __restrict__ Xb,
                         u16* __restrict__ Wb) {
  const int XG = (BS_ * H_) / 4;
  const int WG = (H_ * H_) / 4;  // 2^20
  int i = blockIdx.x * 256 + threadIdx.x;
  const float* src;
  u16* dst;
  int j;
  if (i < XG) {
    src = X; dst = Xb; j = i;
  } else {
    int t = i - XG;
    int w = t >> 20;
    j = t & (WG - 1);
    src = (w == 0) ? Wq : (w == 1) ? Wk : (w == 2) ? Wv : Wo;
    dst = Wb + (size_t)w * (H_ * (size_t)H_);
  }
  float4 v = ((const float4*)src)[j];
  ushort4 o;
  o.x = f2bf(v.x); o.y = f2bf(v.y); o.z = f2bf(v.z); o.w = f2bf(v.w);
  ((ushort4*)dst)[j] = o;
}

// ==== 256x256x64 8-wave double-buffered GEMM: C[m][n] = sum_k A[m*K+k]*B[n*K+k]
// LDS tiles XOR-swizzled: LDS(row, g) = global(row, g ^ (row&7))  [g = 16B group]
// Per K-tile: ONE vmcnt(0)+s_barrier sync; next tile's 8 global_load_lds are
// issued immediately after (into the other buffer), so each load gets a full
// K-iteration (~64 MFMA/wave) of latency cover before its drain. No counted
// vmcnt -> no under-wait race class. Buffer discipline: read buf[kt&1], write
// buf[kt&1^1]; the top-of-iteration barrier separates a buffer's reads (iter
// t-1) from its next writes (iter t).
template <bool F32OUT>
__device__ __forceinline__ void gemm256_core(
    const u16* __restrict__ A, const u16* __restrict__ Bm, void* __restrict__ Cp,
    int N, int K, float scl, int ncut, int bm, int bn,
    u16* lA, u16* lB) {
  const int tid = threadIdx.x;
  const int wave = tid >> 6, lane = tid & 63;
  const int laneRow = lane & 15, laneQ = lane >> 4;
  const int rs = laneRow & 7;                 // reader swizzle key
  const int wm = (wave >> 2) * 128;           // 2 wave-rows x 4 wave-cols
  const int wn = (wave & 3) * 64;

  floatx4 acc[8][4] = {};                     // 128x64 per wave

  // staging: one half-tile (128 rows x 64 cols) = 2 gl_lds16 per thread.
  // wave-instr (w,i) fills LDS rows w*16+i*8 .. +8 linearly; lane l writes
  // row +(l>>3), group (l&7); source col group pre-swizzled by row&7.
  const int srow = lane >> 3;
  const int sg = ((lane & 7) ^ (srow & 7)) * 8;
  const u16* Abase = A + (size_t)(bm + wave * 16 + srow) * K + sg;
  const u16* Bbase = Bm + (size_t)(bn + wave * 16 + srow) * K + sg;
  u16* ldA = lA + wave * 1024;                // element offsets
  u16* ldB = lB + wave * 1024;

  const int NT = K >> 6;

  // prologue: stage K-tile 0 into buf 0
#pragma unroll
  for (int hh = 0; hh < 2; ++hh) {
    const u16* sa = Abase + (size_t)hh * 128 * K;
    gl_lds16(sa, ldA + hh * 8192);
    gl_lds16(sa + (size_t)8 * K, (char*)(ldA + hh * 8192) + 1024);
    const u16* sb = Bbase + (size_t)hh * 128 * K;
    gl_lds16(sb, ldB + hh * 8192);
    gl_lds16(sb + (size_t)8 * K, (char*)(ldB + hh * 8192) + 1024);
  }

  for (int kt = 0; kt < NT; ++kt) {
    const int cur = (kt & 1) * 16384;
    asm volatile("s_waitcnt vmcnt(0)" ::: "memory");  // K-tile kt resident (all waves after barrier)
    asm volatile("s_barrier" ::: "memory");
    if (kt + 1 < NT) {  // stage K-tile kt+1 into the other buffer, issue-early
      const int nxt = 16384 - cur;
      const size_t kc = (size_t)(kt + 1) * 64;
#pragma unroll
      for (int hh = 0; hh < 2; ++hh) {
        const u16* sa = Abase + (size_t)hh * 128 * K + kc;
        gl_lds16(sa, ldA + nxt + hh * 8192);
        gl_lds16(sa + (size_t)8 * K, (char*)(ldA + nxt + hh * 8192) + 1024);
      }
#pragma unroll
      for (int hh = 0; hh < 2; ++hh) {
        const u16* sb = Bbase + (size_t)hh * 128 * K + kc;
        gl_lds16(sb, ldB + nxt + hh * 8192);
        gl_lds16(sb + (size_t)8 * K, (char*)(ldB + nxt + hh * 8192) + 1024);
      }
    }
    __builtin_amdgcn_sched_barrier(0);  // pin stage-issue before reads/MFMA

    bf16x8 bfr[4][2];
#pragma unroll
    for (int nt = 0; nt < 4; ++nt)
#pragma unroll
      for (int ks = 0; ks < 2; ++ks)
        bfr[nt][ks] = *(const bf16x8*)&lB[cur + (wn + nt * 16 + laneRow) * 64 +
                                          ((ks * 4 + laneQ) ^ rs) * 8];
    __builtin_amdgcn_s_setprio(1);
#pragma unroll
    for (int mh = 0; mh < 2; ++mh) {
      bf16x8 afr[4][2];
#pragma unroll
      for (int mt = 0; mt < 4; ++mt)
#pragma unroll
        for (int ks = 0; ks < 2; ++ks)
          afr[mt][ks] = *(const bf16x8*)&lA[cur + (wm + mh * 64 + mt * 16 + laneRow) * 64 +
                                            ((ks * 4 + laneQ) ^ rs) * 8];
#pragma unroll
      for (int mt = 0; mt < 4; ++mt)
#pragma unroll
        for (int nt = 0; nt < 4; ++nt)
#pragma unroll
          for (int ks = 0; ks < 2; ++ks)
            acc[mh * 4 + mt][nt] = mfma16(afr[mt][ks], bfr[nt][ks], acc[mh * 4 + mt][nt]);
    }
    __builtin_amdgcn_s_setprio(0);
  }

  // epilogue
#pragma unroll
  for (int mt = 0; mt < 8; ++mt)
#pragma unroll
    for (int nt = 0; nt < 4; ++nt)
#pragma unroll
      for (int r = 0; r < 4; ++r) {
        int m = bm + wm + mt * 16 + laneQ * 4 + r;
        int n = bn + wn + nt * 16 + laneRow;
        if (F32OUT) {
          ((float*)Cp)[(size_t)m * N + n] = acc[mt][nt][r];
        } else {
          float s = (n < ncut) ? scl : 1.0f;
          ((u16*)Cp)[(size_t)m * N + n] = f2bf(acc[mt][nt][r] * s);
        }
      }
}

// fused QK-projection (256 blocks) + Vt (128 blocks): Vt overlaps QK's tail
__global__ __launch_bounds__(512, 2)
void gemm256_pair(const u16* __restrict__ Xb, const u16* __restrict__ Wqb,
                  u16* __restrict__ QKb, const u16* __restrict__ Wvb,
                  u16* __restrict__ Vtb) {
  __shared__ __attribute__((aligned(16))) u16 lA[2][16384];
  __shared__ __attribute__((aligned(16))) u16 lB[2][16384];
  const int bid = blockIdx.x;
  if (bid < 256) {
    gemm256_core<false>(Xb, Wqb, QKb, 4096, 2048, SCL_Q, 2048,
                        (bid >> 4) * 256, (bid & 15) * 256, &lA[0][0], &lB[0][0]);
  } else {
    const int t = bid - 256;
    gemm256_core<false>(Wvb, Xb, Vtb, 4096, 2048, 1.0f, 0,
                        (t >> 4) * 256, (t & 15) * 256, &lA[0][0], &lB[0][0]);
  }
}

__global__ __launch_bounds__(512, 2)
void gemm256_out(const u16* __restrict__ AOb, const u16* __restrict__ Wob,
                 float* __restrict__ Out) {
  __shared__ __attribute__((aligned(16))) u16 lA[2][16384];
  __shared__ __attribute__((aligned(16))) u16 lB[2][16384];
  gemm256_core<true>(AOb, Wob, Out, 2048, 2048, 1.0f, 0,
                     (int)blockIdx.y * 256, (int)blockIdx.x * 256,
                     &lA[0][0], &lB[0][0]);
}

// ---- flash attention, fixed-max softmax, key-chunked for balance.
// (ROUND-0 VERBATIM: serialized staging, no setprio. The pipelined variant
// regressed 110->133us: it desynchronized the same-head L2 convoy (FETCH
// 141->165MB) and doubled per-iter drain points; inter-block TLP at 3
// blocks/CU already hides staging latency.)
// QKg: [BS][4096] (cols 0..2047 Q pre-scaled, 2048..4095 K), Vt: [H][BS], Og: [BS][H]
__global__ __launch_bounds__(256, 3)
void flash_attn(const u16* __restrict__ QKg, const u16* __restrict__ Vt,
                u16* __restrict__ Og, float* __restrict__ Part,
                float* __restrict__ Lp) {
  __shared__ __attribute__((aligned(16))) u16 smem[64 * 128 + 128 * 64 + 128 * PSTR];
  u16* lK = smem;                // [64 keys][128 hd]
  u16* lV = smem + 8192;         // [128 hd][64 keys]
  u16* lP = smem + 16384;        // [128 q][PSTR]

  const int tid = threadIdx.x;
  const int wave = tid >> 6, lane = tid & 63;
  const int laneRow = lane & 15, laneQ = lane >> 4;
  const int rs = laneRow & 7;  // reader swizzle key
  const int wq = wave * 32;
  const int bx = blockIdx.x, bh = blockIdx.y;
  const int b = bh >> 4, h = bh & 15;

  int qt, ktBeg, ktEnd, ch;
  if (bx < 16) {
    qt = 15 - (bx >> 1);
    ch = bx & 1;
    ktBeg = ch * (qt + 1);
    ktEnd = ktBeg + (qt + 1);
  } else {
    qt = 23 - bx;
    ch = 0;
    ktBeg = 0;
    ktEnd = 2 * (qt + 1);
  }
  const bool partial = (bx < 16);

  // staging swizzle keys
  const int c16 = (((tid & 15) ^ ((tid >> 4) & 7)) * 8);  // 16-group rows (Q,K)
  const int c8s = (((tid & 7) ^ ((tid >> 3) & 7)) * 8);   // 8-group rows (V)

  // ---- stage Q tile [128][128] (swizzled), load fragments
  {
    const int r = tid >> 4;
    const u16* Qp = QKg + (size_t)(b * S_ + qt * 128 + r) * QKSTR + h * 128 + c16;
    char* ld = (char*)smem + wave * 1024;
#pragma unroll
    for (int i = 0; i < 8; ++i)
      gl_lds16(Qp + (size_t)i * 16 * QKSTR, ld + i * 4096);
  }
  __syncthreads();
  bf16x8 qf[2][4];
#pragma unroll
  for (int mt = 0; mt < 2; ++mt)
#pragma unroll
    for (int ks = 0; ks < 4; ++ks)
      qf[mt][ks] = *(const bf16x8*)&smem[(wq + mt * 16 + laneRow) * 128 +
                                         (((ks * 4 + laneQ) ^ rs) * 8)];

  floatx4 accO[2][8] = {};
  float ps[2][4] = {};

  for (int kt = ktBeg; kt < ktEnd; ++kt) {
    __syncthreads();  // previous-iter LDS reads (or qf reads) done before overwrite
    {  // stage K tile [64][128] swizzled
      const int r = tid >> 4;
      const u16* Kp = QKg + 2048 + (size_t)(b * S_ + kt * 64 + r) * QKSTR + h * 128 + c16;
      char* ld = (char*)lK + wave * 1024;
#pragma unroll
      for (int i = 0; i < 4; ++i)
        gl_lds16(Kp + (size_t)i * 16 * QKSTR, ld + i * 4096);
    }
    {  // stage V^T tile [128][64] swizzled
      const int r = tid >> 3;
      const u16* Vp = Vt + (size_t)(h * 128 + r) * BS_ + b * S_ + kt * 64 + c8s;
      char* ld = (char*)lV + wave * 1024;
#pragma unroll
      for (int i = 0; i < 4; ++i)
        gl_lds16(Vp + (size_t)i * 32 * BS_, ld + i * 4096);
    }
    __syncthreads();  // staging drained

    // ---- S = Q K^T (Q pre-scaled, base-2 domain)
    floatx4 accS[2][4] = {};
#pragma unroll
    for (int ks = 0; ks < 4; ++ks) {
      bf16x8 kf[4];
#pragma unroll
      for (int nt = 0; nt < 4; ++nt)
        kf[nt] = *(const bf16x8*)&lK[(nt * 16 + laneRow) * 128 +
                                     (((ks * 4 + laneQ) ^ rs) * 8)];
#pragma unroll
      for (int mt = 0; mt < 2; ++mt)
#pragma unroll
        for (int nt = 0; nt < 4; ++nt)
          accS[mt][nt] = mfma16(qf[mt][ks], kf[nt], accS[mt][nt]);
    }
    if (kt * 64 + 63 > qt * 128 + wq) {  // causal boundary for this wave
#pragma unroll
      for (int mt = 0; mt < 2; ++mt)
#pragma unroll
        for (int r = 0; r < 4; ++r) {
          int q = qt * 128 + wq + mt * 16 + laneQ * 4 + r;
#pragma unroll
          for (int nt = 0; nt < 4; ++nt) {
            int k = kt * 64 + nt * 16 + laneRow;
            if (k > q) accS[mt][nt][r] = -1e30f;
          }
        }
    }

    // ---- fixed-max softmax: p = exp2(s); lane-local row-sum accumulation
#pragma unroll
    for (int mt = 0; mt < 2; ++mt)
#pragma unroll
      for (int r = 0; r < 4; ++r) {
#pragma unroll
        for (int nt = 0; nt < 4; ++nt) {
          float p = exp2f(accS[mt][nt][r]);
          accS[mt][nt][r] = p;
          ps[mt][r] += p;
        }
      }
    // P: C-layout -> LDS -> A-layout (wave-private rows, no barrier)
#pragma unroll
    for (int mt = 0; mt < 2; ++mt)
#pragma unroll
      for (int nt = 0; nt < 4; ++nt)
#pragma unroll
        for (int r = 0; r < 4; ++r)
          lP[(wq + mt * 16 + laneQ * 4 + r) * PSTR + nt * 16 + laneRow] =
              f2bf(accS[mt][nt][r]);

    // ---- O += P V
#pragma unroll
    for (int ks = 0; ks < 2; ++ks) {
      bf16x8 pf[2], vf[8];
#pragma unroll
      for (int mt = 0; mt < 2; ++mt)
        pf[mt] = *(const bf16x8*)&lP[(wq + mt * 16 + laneRow) * PSTR + ks * 32 + laneQ * 8];
#pragma unroll
      for (int nt = 0; nt < 8; ++nt)
        vf[nt] = *(const bf16x8*)&lV[(nt * 16 + laneRow) * 64 +
                                     (((ks * 4 + laneQ) ^ rs) * 8)];
#pragma unroll
      for (int mt = 0; mt < 2; ++mt)
#pragma unroll
        for (int nt = 0; nt < 8; ++nt)
          accO[mt][nt] = mfma16(pf[mt], vf[nt], accO[mt][nt]);
    }
  }

  // ---- epilogue: reduce row sums across the 16 col-lanes (once per kernel)
  float li[2][4];
#pragma unroll
  for (int mt = 0; mt < 2; ++mt)
#pragma unroll
    for (int r = 0; r < 4; ++r) {
      float l = ps[mt][r];
#pragma unroll
      for (int off = 1; off < 16; off <<= 1)
        l += __shfl_xor(l, off);
      li[mt][r] = l;
    }

  if (!partial) {
#pragma unroll
    for (int mt = 0; mt < 2; ++mt)
#pragma unroll
      for (int r = 0; r < 4; ++r) {
        float inv = 1.0f / li[mt][r];
        int m = qt * 128 + wq + mt * 16 + laneQ * 4 + r;
#pragma unroll
        for (int nt = 0; nt < 8; ++nt) {
          int n = nt * 16 + laneRow;
          Og[(size_t)(b * S_ + m) * H_ + h * 128 + n] = f2bf(accO[mt][nt][r] * inv);
        }
      }
  } else {
    float* P0 = Part + (size_t)ch * PART_CH;
    float* L0 = Lp + (size_t)ch * LP_CH;
#pragma unroll
    for (int mt = 0; mt < 2; ++mt)
#pragma unroll
      for (int r = 0; r < 4; ++r) {
        int qrow = wq + mt * 16 + laneQ * 4 + r;
        int pIdx = ((qt - 8) * 32 + bh) * 128 + qrow;
        if (laneRow == 0) L0[pIdx] = li[mt][r];
#pragma unroll
        for (int nt = 0; nt < 8; ++nt)
          P0[(size_t)pIdx * 128 + nt * 16 + laneRow] = accO[mt][nt][r];
      }
  }
}

// ---- merge the two key-chunk partials for qt>=8, normalize, write bf16
__global__ void combine(const float* __restrict__ Part, const float* __restrict__ Lp,
                        u16* __restrict__ Og) {
  int j = blockIdx.x * 256 + threadIdx.x;  // float4 index over one chunk
  int e = j * 4;
  int d = e & 127;
  int rowid = e >> 7;  // 0..32767 : ((qt-8)*32 + bh)*128 + q
  float4 a = ((const float4*)Part)[j];
  float4 c = ((const float4*)(Part + PART_CH))[j];
  float inv = 1.0f / (Lp[rowid] + Lp[LP_CH + rowid]);
  int q = rowid & 127;
  int bh = (rowid >> 7) & 31;
  int qt = 8 + (rowid >> 12);
  int b = bh >> 4, h = bh & 15;
  int m = qt * 128 + q;
  ushort4 o;
  o.x = f2bf((a.x + c.x) * inv);
  o.y = f2bf((a.y + c.y) * inv);
  o.z = f2bf((a.z + c.z) * inv);
  o.w = f2bf((a.w + c.w) * inv);
  *(ushort4*)&Og[(size_t)(b * S_ + m) * H_ + h * 128 + d] = o;
}

extern "C" void kernel_launch(void* const* d_in, const int* in_sizes, int n_in,
                              void* d_out, int out_size, void* d_ws, size_t ws_size,
                              hipStream_t stream) {
  const float* X  = (const float*)d_in[0];
  // d_in[1] = attention_mask (exactly causal; handled analytically)
  const float* Wq = (const float*)d_in[2];
  const float* Wk = (const float*)d_in[3];
  const float* Wv = (const float*)d_in[4];
  const float* Wo = (const float*)d_in[5];

  char* ws = (char*)d_ws;
  u16* Xb  = (u16*)(ws);                // 16 MB [BS][H]           (dead after GEMMs)
  u16* Wqb = (u16*)(ws + (16u << 20));  // 32 MB Wq,Wk,Wv,Wo bf16  (Wq..Wv dead after GEMMs)
  u16* Wvb = Wqb + 2 * (size_t)H_ * H_;
  u16* Wob = Wqb + 3 * (size_t)H_ * H_; // [40,48) MB — needed till the end
  u16* QKb = (u16*)(ws + (48u << 20));  // 32 MB [BS][4096]
  u16* Vtb = (u16*)(ws + (80u << 20));  // 16 MB [H][BS]
  u16* AOb = (u16*)(ws + (96u << 20));  // 16 MB [BS][H]
  // flash partials overlay dead regions [0, 33.8 MB)
  float* Part = (float*)ws;
  float* Lp   = (float*)(ws + 2u * PART_CH * sizeof(float));

  {
    int groups = (BS_ * H_) / 4 + H_ * H_;
    cast_all<<<groups / 256, 256, 0, stream>>>(X, Wq, Wk, Wv, Wo, Xb, Wqb);
  }

  // fused: QK projection (Q cols pre-scaled) 256 blocks + Vt = Wv*X^T 128 blocks
  gemm256_pair<<<dim3(384), 512, 0, stream>>>(Xb, Wqb, QKb, Wvb, Vtb);

  flash_attn<<<dim3(24, B_ * NH_), 256, 0, stream>>>(QKb, Vtb, AOb, Part, Lp);
  combine<<<PART_CH / 4 / 256, 256, 0, stream>>>(Part, Lp, AOb);

  gemm256_out<<<dim3(8, 16), 512, 0, stream>>>(AOb, Wob, (float*)d_out);
}

// Round 4
// 389.365 us; speedup vs baseline: 1.1637x; 1.1637x over previous
//
#include <hip/hip_runtime.h>

typedef unsigned short u16;
typedef __bf16 bf16x8 __attribute__((ext_vector_type(8)));
typedef float floatx4 __attribute__((ext_vector_type(4)));

#define B_ 2
#define S_ 2048
#define H_ 2048
#define NH_ 16
#define BS_ 4096   // B_*S_
#define QKSTR 4096 // row stride of fused QK buffer
#define PSTR 72    // P LDS row stride (elements)

// softmax scale folded into Q at GEMM epilogue: hd^-0.5 * log2(e)
#define SCL_Q (0.08838834764831843f * 1.4426950408889634f)

// partial buffers (fixed-max softmax => partials are additive)
#define PART_CH 4194304   // floats per chunk: 8 qt * 32 bh * 128 q * 128 hd
#define LP_CH 32768       // floats per chunk: 8 * 32 * 128

__device__ __forceinline__ u16 f2bf(float f) {
  unsigned u = __float_as_uint(f);
  u += 0x7fffu + ((u >> 16) & 1u);  // RNE
  return (u16)(u >> 16);
}

__device__ __forceinline__ void gl_lds16(const void* g, void* l) {
  __builtin_amdgcn_global_load_lds((__attribute__((address_space(1))) void*)g,
                                   (__attribute__((address_space(3))) void*)l,
                                   16, 0, 0);
}

__device__ __forceinline__ floatx4 mfma16(bf16x8 a, bf16x8 b, floatx4 c) {
  return __builtin_amdgcn_mfma_f32_16x16x32_bf16(a, b, c, 0, 0, 0);
}

// ---- fused fp32->bf16 cast: X (BS*H) then Wq,Wk,Wv,Wo (H*H each)
__global__ void cast_all(const float* __restrict__ X, const float* __restrict__ Wq,
                         const float* __restrict__ Wk, const float* __restrict__ Wv,
                         const float* __restrict__ Wo, u16* __restrict__ Xb,
                         u16* __restrict__ Wb) {
  const int XG = (BS_ * H_) / 4;
  const int WG = (H_ * H_) / 4;  // 2^20
  int i = blockIdx.x * 256 + threadIdx.x;
  const float* src;
  u16* dst;
  int j;
  if (i < XG) {
    src = X; dst = Xb; j = i;
  } else {
    int t = i - XG;
    int w = t >> 20;
    j = t & (WG - 1);
    src = (w == 0) ? Wq : (w == 1) ? Wk : (w == 2) ? Wv : Wo;
    dst = Wb + (size_t)w * (H_ * (size_t)H_);
  }
  float4 v = ((const float4*)src)[j];
  ushort4 o;
  o.x = f2bf(v.x); o.y = f2bf(v.y); o.z = f2bf(v.z); o.w = f2bf(v.w);
  ((ushort4*)dst)[j] = o;
}

// ==== 128x256x64 8-wave TRIPLE-buffered GEMM, depth-2 prefetch, counted vmcnt.
// C[m][n] = sum_k A[m*K+k]*B[n*K+k].
// LDS per buffer: lA[128][64] (16KB) + lB[256][64] (32KB) = 48KB; 3 bufs = 144KB.
// XOR swizzle: LDS(row, g) = global(row, g ^ (row&7))  [g = 16B group].
//
// Schedule: prologue stages tiles 0,1. Iteration kt: wait vmcnt(6) (all but
// the newest 6 loads drained -> tile kt resident, since each thread issues
// exactly 6 loads/tile in order), barrier, issue tile kt+2 into buf (kt+2)%3,
// then compute tile kt. Loads get ~2 K-iterations of latency cover. Last
// iteration waits vmcnt(0) (no younger loads exist -> vmcnt(6) would
// under-wait). Buffer (kt+2)%3 was last read in iteration kt-1, which every
// wave finished before the top-of-kt barrier -> no read/write overlap.
template <bool F32OUT>
__global__ __launch_bounds__(512, 2)
void gemm3(const u16* __restrict__ A, const u16* __restrict__ Bm,
           void* __restrict__ Cp, int N, int K, float scl, int ncut) {
  __shared__ __attribute__((aligned(16))) u16 smem[3 * 24576];  // 144KB
  const int tid = threadIdx.x;
  const int wave = tid >> 6, lane = tid & 63;
  const int laneRow = lane & 15, laneQ = lane >> 4;
  const int rs = laneRow & 7;                 // reader swizzle key
  const int bm = blockIdx.y * 128, bn = blockIdx.x * 256;
  const int wm = (wave >> 2) * 64;            // 2 wave-rows x 4 wave-cols
  const int wn = (wave & 3) * 64;

  floatx4 acc[4][4] = {};                     // 64x64 per wave

  // staging: sweep = 512 threads x 16B = 8KB = 64 rows x 128B.
  // thread tid -> row tid>>3, 16B-group tid&7; source group inverse-swizzled.
  const int srow = tid >> 3;                  // 0..63
  const int sg = (((tid & 7) ^ (srow & 7)) * 8);
  const u16* Abase = A + (size_t)(bm + srow) * K + sg;
  const u16* Bbase = Bm + (size_t)(bn + srow) * K + sg;
  const int NT = K >> 6;

  // buf layout (bytes): [0,16K) = A rows 0..127; [16K,48K) = B rows 0..255.
  auto stage = [&](int buf, int kc) {
    char* base = (char*)smem + buf * 49152 + wave * 1024;  // wave-uniform dest
#pragma unroll
    for (int i = 0; i < 2; ++i)               // A: 2 sweeps (rows i*64..)
      gl_lds16(Abase + (size_t)(i * 64) * K + kc, base + i * 8192);
#pragma unroll
    for (int j = 0; j < 4; ++j)               // B: 4 sweeps (rows j*64..)
      gl_lds16(Bbase + (size_t)(j * 64) * K + kc, base + 16384 + j * 8192);
  };

  // prologue: tiles 0 and 1
  stage(0, 0);
  stage(1, 64);

  int cur = 0;
  for (int kt = 0; kt < NT; ++kt) {
    if (kt < NT - 1)
      asm volatile("s_waitcnt vmcnt(6)" ::: "memory");  // tile kt resident
    else
      asm volatile("s_waitcnt vmcnt(0)" ::: "memory");  // final tile: full drain
    asm volatile("s_barrier" ::: "memory");
    if (kt + 2 < NT) {
      int nb = cur + 2; if (nb >= 3) nb -= 3;
      stage(nb, (kt + 2) << 6);               // depth-2 prefetch
    }
    __builtin_amdgcn_sched_barrier(0);        // pin stage-issue before reads/MFMA

    const u16* bp = smem + cur * 24576;       // element offset
    bf16x8 af[4][2], bf[4][2];
#pragma unroll
    for (int mt = 0; mt < 4; ++mt)
#pragma unroll
      for (int ks = 0; ks < 2; ++ks)
        af[mt][ks] = *(const bf16x8*)&bp[(wm + mt * 16 + laneRow) * 64 +
                                         ((ks * 4 + laneQ) ^ rs) * 8];
#pragma unroll
    for (int nt = 0; nt < 4; ++nt)
#pragma unroll
      for (int ks = 0; ks < 2; ++ks)
        bf[nt][ks] = *(const bf16x8*)&bp[8192 + (wn + nt * 16 + laneRow) * 64 +
                                         ((ks * 4 + laneQ) ^ rs) * 8];
    __builtin_amdgcn_s_setprio(1);
#pragma unroll
    for (int mt = 0; mt < 4; ++mt)
#pragma unroll
      for (int nt = 0; nt < 4; ++nt)
#pragma unroll
        for (int ks = 0; ks < 2; ++ks)
          acc[mt][nt] = mfma16(af[mt][ks], bf[nt][ks], acc[mt][nt]);
    __builtin_amdgcn_s_setprio(0);

    cur += 1; if (cur == 3) cur = 0;
  }

  // epilogue
#pragma unroll
  for (int mt = 0; mt < 4; ++mt)
#pragma unroll
    for (int nt = 0; nt < 4; ++nt)
#pragma unroll
      for (int r = 0; r < 4; ++r) {
        int m = bm + wm + mt * 16 + laneQ * 4 + r;
        int n = bn + wn + nt * 16 + laneRow;
        if (F32OUT) {
          ((float*)Cp)[(size_t)m * N + n] = acc[mt][nt][r];
        } else {
          float s = (n < ncut) ? scl : 1.0f;
          ((u16*)Cp)[(size_t)m * N + n] = f2bf(acc[mt][nt][r] * s);
        }
      }
}

// ---- flash attention, fixed-max softmax, key-chunked for balance.
// (ROUND-0 VERBATIM: serialized staging, no setprio. The pipelined variant
// regressed 110->133us: it desynchronized the same-head L2 convoy and doubled
// per-iter drain points; inter-block TLP at 3 blocks/CU already hides staging.)
// QKg: [BS][4096] (cols 0..2047 Q pre-scaled, 2048..4095 K), Vt: [H][BS], Og: [BS][H]
__global__ __launch_bounds__(256, 3)
void flash_attn(const u16* __restrict__ QKg, const u16* __restrict__ Vt,
                u16* __restrict__ Og, float* __restrict__ Part,
                float* __restrict__ Lp) {
  __shared__ __attribute__((aligned(16))) u16 smem[64 * 128 + 128 * 64 + 128 * PSTR];
  u16* lK = smem;                // [64 keys][128 hd]
  u16* lV = smem + 8192;         // [128 hd][64 keys]
  u16* lP = smem + 16384;        // [128 q][PSTR]

  const int tid = threadIdx.x;
  const int wave = tid >> 6, lane = tid & 63;
  const int laneRow = lane & 15, laneQ = lane >> 4;
  const int rs = laneRow & 7;  // reader swizzle key
  const int wq = wave * 32;
  const int bx = blockIdx.x, bh = blockIdx.y;
  const int b = bh >> 4, h = bh & 15;

  int qt, ktBeg, ktEnd, ch;
  if (bx < 16) {
    qt = 15 - (bx >> 1);
    ch = bx & 1;
    ktBeg = ch * (qt + 1);
    ktEnd = ktBeg + (qt + 1);
  } else {
    qt = 23 - bx;
    ch = 0;
    ktBeg = 0;
    ktEnd = 2 * (qt + 1);
  }
  const bool partial = (bx < 16);

  // staging swizzle keys
  const int c16 = (((tid & 15) ^ ((tid >> 4) & 7)) * 8);  // 16-group rows (Q,K)
  const int c8s = (((tid & 7) ^ ((tid >> 3) & 7)) * 8);   // 8-group rows (V)

  // ---- stage Q tile [128][128] (swizzled), load fragments
  {
    const int r = tid >> 4;
    const u16* Qp = QKg + (size_t)(b * S_ + qt * 128 + r) * QKSTR + h * 128 + c16;
    char* ld = (char*)smem + wave * 1024;
#pragma unroll
    for (int i = 0; i < 8; ++i)
      gl_lds16(Qp + (size_t)i * 16 * QKSTR, ld + i * 4096);
  }
  __syncthreads();
  bf16x8 qf[2][4];
#pragma unroll
  for (int mt = 0; mt < 2; ++mt)
#pragma unroll
    for (int ks = 0; ks < 4; ++ks)
      qf[mt][ks] = *(const bf16x8*)&smem[(wq + mt * 16 + laneRow) * 128 +
                                         (((ks * 4 + laneQ) ^ rs) * 8)];

  floatx4 accO[2][8] = {};
  float ps[2][4] = {};

  for (int kt = ktBeg; kt < ktEnd; ++kt) {
    __syncthreads();  // previous-iter LDS reads (or qf reads) done before overwrite
    {  // stage K tile [64][128] swizzled
      const int r = tid >> 4;
      const u16* Kp = QKg + 2048 + (size_t)(b * S_ + kt * 64 + r) * QKSTR + h * 128 + c16;
      char* ld = (char*)lK + wave * 1024;
#pragma unroll
      for (int i = 0; i < 4; ++i)
        gl_lds16(Kp + (size_t)i * 16 * QKSTR, ld + i * 4096);
    }
    {  // stage V^T tile [128][64] swizzled
      const int r = tid >> 3;
      const u16* Vp = Vt + (size_t)(h * 128 + r) * BS_ + b * S_ + kt * 64 + c8s;
      char* ld = (char*)lV + wave * 1024;
#pragma unroll
      for (int i = 0; i < 4; ++i)
        gl_lds16(Vp + (size_t)i * 32 * BS_, ld + i * 4096);
    }
    __syncthreads();  // staging drained

    // ---- S = Q K^T (Q pre-scaled, base-2 domain)
    floatx4 accS[2][4] = {};
#pragma unroll
    for (int ks = 0; ks < 4; ++ks) {
      bf16x8 kf[4];
#pragma unroll
      for (int nt = 0; nt < 4; ++nt)
        kf[nt] = *(const bf16x8*)&lK[(nt * 16 + laneRow) * 128 +
                                     (((ks * 4 + laneQ) ^ rs) * 8)];
#pragma unroll
      for (int mt = 0; mt < 2; ++mt)
#pragma unroll
        for (int nt = 0; nt < 4; ++nt)
          accS[mt][nt] = mfma16(qf[mt][ks], kf[nt], accS[mt][nt]);
    }
    if (kt * 64 + 63 > qt * 128 + wq) {  // causal boundary for this wave
#pragma unroll
      for (int mt = 0; mt < 2; ++mt)
#pragma unroll
        for (int r = 0; r < 4; ++r) {
          int q = qt * 128 + wq + mt * 16 + laneQ * 4 + r;
#pragma unroll
          for (int nt = 0; nt < 4; ++nt) {
            int k = kt * 64 + nt * 16 + laneRow;
            if (k > q) accS[mt][nt][r] = -1e30f;
          }
        }
    }

    // ---- fixed-max softmax: p = exp2(s); lane-local row-sum accumulation
#pragma unroll
    for (int mt = 0; mt < 2; ++mt)
#pragma unroll
      for (int r = 0; r < 4; ++r) {
#pragma unroll
        for (int nt = 0; nt < 4; ++nt) {
          float p = exp2f(accS[mt][nt][r]);
          accS[mt][nt][r] = p;
          ps[mt][r] += p;
        }
      }
    // P: C-layout -> LDS -> A-layout (wave-private rows, no barrier)
#pragma unroll
    for (int mt = 0; mt < 2; ++mt)
#pragma unroll
      for (int nt = 0; nt < 4; ++nt)
#pragma unroll
        for (int r = 0; r < 4; ++r)
          lP[(wq + mt * 16 + laneQ * 4 + r) * PSTR + nt * 16 + laneRow] =
              f2bf(accS[mt][nt][r]);

    // ---- O += P V
#pragma unroll
    for (int ks = 0; ks < 2; ++ks) {
      bf16x8 pf[2], vf[8];
#pragma unroll
      for (int mt = 0; mt < 2; ++mt)
        pf[mt] = *(const bf16x8*)&lP[(wq + mt * 16 + laneRow) * PSTR + ks * 32 + laneQ * 8];
#pragma unroll
      for (int nt = 0; nt < 8; ++nt)
        vf[nt] = *(const bf16x8*)&lV[(nt * 16 + laneRow) * 64 +
                                     (((ks * 4 + laneQ) ^ rs) * 8)];
#pragma unroll
      for (int mt = 0; mt < 2; ++mt)
#pragma unroll
        for (int nt = 0; nt < 8; ++nt)
          accO[mt][nt] = mfma16(pf[mt], vf[nt], accO[mt][nt]);
    }
  }

  // ---- epilogue: reduce row sums across the 16 col-lanes (once per kernel)
  float li[2][4];
#pragma unroll
  for (int mt = 0; mt < 2; ++mt)
#pragma unroll
    for (int r = 0; r < 4; ++r) {
      float l = ps[mt][r];
#pragma unroll
      for (int off = 1; off < 16; off <<= 1)
        l += __shfl_xor(l, off);
      li[mt][r] = l;
    }

  if (!partial) {
#pragma unroll
    for (int mt = 0; mt < 2; ++mt)
#pragma unroll
      for (int r = 0; r < 4; ++r) {
        float inv = 1.0f / li[mt][r];
        int m = qt * 128 + wq + mt * 16 + laneQ * 4 + r;
#pragma unroll
        for (int nt = 0; nt < 8; ++nt) {
          int n = nt * 16 + laneRow;
          Og[(size_t)(b * S_ + m) * H_ + h * 128 + n] = f2bf(accO[mt][nt][r] * inv);
        }
      }
  } else {
    float* P0 = Part + (size_t)ch * PART_CH;
    float* L0 = Lp + (size_t)ch * LP_CH;
#pragma unroll
    for (int mt = 0; mt < 2; ++mt)
#pragma unroll
      for (int r = 0; r < 4; ++r) {
        int qrow = wq + mt * 16 + laneQ * 4 + r;
        int pIdx = ((qt - 8) * 32 + bh) * 128 + qrow;
        if (laneRow == 0) L0[pIdx] = li[mt][r];
#pragma unroll
        for (int nt = 0; nt < 8; ++nt)
          P0[(size_t)pIdx * 128 + nt * 16 + laneRow] = accO[mt][nt][r];
      }
  }
}

// ---- merge the two key-chunk partials for qt>=8, normalize, write bf16
__global__ void combine(const float* __restrict__ Part, const float* __restrict__ Lp,
                        u16* __restrict__ Og) {
  int j = blockIdx.x * 256 + threadIdx.x;  // float4 index over one chunk
  int e = j * 4;
  int d = e & 127;
  int rowid = e >> 7;  // 0..32767 : ((qt-8)*32 + bh)*128 + q
  float4 a = ((const float4*)Part)[j];
  float4 c = ((const float4*)(Part + PART_CH))[j];
  float inv = 1.0f / (Lp[rowid] + Lp[LP_CH + rowid]);
  int q = rowid & 127;
  int bh = (rowid >> 7) & 31;
  int qt = 8 + (rowid >> 12);
  int b = bh >> 4, h = bh & 15;
  int m = qt * 128 + q;
  ushort4 o;
  o.x = f2bf((a.x + c.x) * inv);
  o.y = f2bf((a.y + c.y) * inv);
  o.z = f2bf((a.z + c.z) * inv);
  o.w = f2bf((a.w + c.w) * inv);
  *(ushort4*)&Og[(size_t)(b * S_ + m) * H_ + h * 128 + d] = o;
}

extern "C" void kernel_launch(void* const* d_in, const int* in_sizes, int n_in,
                              void* d_out, int out_size, void* d_ws, size_t ws_size,
                              hipStream_t stream) {
  const float* X  = (const float*)d_in[0];
  // d_in[1] = attention_mask (exactly causal; handled analytically)
  const float* Wq = (const float*)d_in[2];
  const float* Wk = (const float*)d_in[3];
  const float* Wv = (const float*)d_in[4];
  const float* Wo = (const float*)d_in[5];

  char* ws = (char*)d_ws;
  u16* Xb  = (u16*)(ws);                // 16 MB [BS][H]           (dead after GEMMs)
  u16* Wqb = (u16*)(ws + (16u << 20));  // 32 MB Wq,Wk,Wv,Wo bf16  (Wq..Wv dead after GEMMs)
  u16* Wvb = Wqb + 2 * (size_t)H_ * H_;
  u16* Wob = Wqb + 3 * (size_t)H_ * H_; // [40,48) MB — needed till the end
  u16* QKb = (u16*)(ws + (48u << 20));  // 32 MB [BS][4096]
  u16* Vtb = (u16*)(ws + (80u << 20));  // 16 MB [H][BS]
  u16* AOb = (u16*)(ws + (96u << 20));  // 16 MB [BS][H]
  // flash partials overlay dead regions [0, 33.8 MB)
  float* Part = (float*)ws;
  float* Lp   = (float*)(ws + 2u * PART_CH * sizeof(float));

  {
    int groups = (BS_ * H_) / 4 + H_ * H_;
    cast_all<<<groups / 256, 256, 0, stream>>>(X, Wq, Wk, Wv, Wo, Xb, Wqb);
  }

  // fused Q|K projection; Q columns pre-scaled by SCL_Q. grid 16x32 = 512 = 2 clean rounds
  gemm3<false><<<dim3(16, 32), 512, 0, stream>>>(Xb, Wqb, QKb, 4096, 2048, SCL_Q, 2048);
  // Vt = Wv * X^T -> [H][BS]. grid 16x16 = 256 = 1 clean round
  gemm3<false><<<dim3(16, 16), 512, 0, stream>>>(Wvb, Xb, Vtb, 4096, 2048, 1.0f, 0);

  flash_attn<<<dim3(24, B_ * NH_), 256, 0, stream>>>(QKb, Vtb, AOb, Part, Lp);
  combine<<<PART_CH / 4 / 256, 256, 0, stream>>>(Part, Lp, AOb);

  // out = AO * Wo^T (fp32). grid 8x32 = 256 = 1 clean round
  gemm3<true><<<dim3(8, 32), 512, 0, stream>>>(AOb, Wob, (float*)d_out, 2048, 2048, 1.0f, 0);
}